// Round 9
// baseline (317.621 us; speedup 1.0000x reference)
//
#include <hip/hip_runtime.h>

#define N_NODES 100000
#define N_EDGES 1600000
#define BSHIFT 7
#define NBUCK 782     // ceil(N_NODES/128)
#define NCHUNK 1000
#define CH 1600       // N_EDGES / NCHUNK exactly

typedef __attribute__((ext_vector_type(8))) short bf16x8;
typedef __attribute__((ext_vector_type(4))) float f32x4;

// bf16 helpers (RTNE pack; unpack = shift to high half)
__device__ __forceinline__ unsigned pack_bf16x2(float a, float b) {
  unsigned ua = __float_as_uint(a);
  unsigned ub = __float_as_uint(b);
  ua = ua + 0x7fffu + ((ua >> 16) & 1u);
  ub = ub + 0x7fffu + ((ub >> 16) & 1u);
  return (ua >> 16) | (ub & 0xffff0000u);
}
__device__ __forceinline__ unsigned short bf16u(float f) {
  unsigned u = __float_as_uint(f);
  u = u + 0x7fffu + ((u >> 16) & 1u);
  return (unsigned short)(u >> 16);
}
__device__ __forceinline__ float bf_lo(unsigned u) { return __uint_as_float(u << 16); }
__device__ __forceinline__ float bf_hi(unsigned u) { return __uint_as_float(u & 0xffff0000u); }

// ---------------- weight prep: transpose + bf16 (once) ----------------

__global__ __launch_bounds__(256) void k_prepw(const float* __restrict__ W1,
                                               const float* __restrict__ W2,
                                               unsigned short* __restrict__ Wt1,
                                               unsigned short* __restrict__ Wt2) {
  int t = blockIdx.x * 256 + threadIdx.x;
  if (t < 128 * 128) {
    int n = t >> 7, k = t & 127;
    Wt1[n * 128 + k] = bf16u(W1[k * 128 + n]);
  }
  if (t < 48 * 128) {
    int n = t >> 7, k = t & 127;
    float v = (n < 40) ? W2[k * 40 + n] : 0.f;
    Wt2[n * 128 + k] = bf16u(v);
  }
}

// ---------------- counting-sort partition, BOTH src and dst (no global atomics) ----------------
// histG layout: [chunk][bucket] — hist writes and part reads are contiguous per block.

__global__ __launch_bounds__(256) void k_hist(const int* __restrict__ src,
                                              const int* __restrict__ dst,
                                              unsigned* __restrict__ histGd,
                                              unsigned* __restrict__ histGs) {
  __shared__ unsigned hd[NBUCK];
  __shared__ unsigned hs[NBUCK];
  const int t = threadIdx.x, j = blockIdx.x;
  for (int i = t; i < NBUCK; i += 256) { hd[i] = 0u; hs[i] = 0u; }
  __syncthreads();
  const int e0 = j * CH;
  for (int e = e0 + t; e < e0 + CH; e += 256) {
    atomicAdd(&hd[(unsigned)dst[e] >> BSHIFT], 1u);
    atomicAdd(&hs[(unsigned)src[e] >> BSHIFT], 1u);
  }
  __syncthreads();
  for (int i = t; i < NBUCK; i += 256) {
    histGd[(size_t)j * NBUCK + i] = hd[i];
    histGs[(size_t)j * NBUCK + i] = hs[i];
  }
}

// block per (bucket, stream): exclusive scan of NCHUNK chunk-counts in place + total.
// Scan order is XCD-grouped: chunks with j%8==g get consecutive offset ranges, so
// concurrent same-XCD blocks write adjacent ebuf slots -> L2 absorbs line sharing.
__global__ __launch_bounds__(256) void k_offs(unsigned* __restrict__ histGd,
                                              unsigned* __restrict__ histGs,
                                              unsigned* __restrict__ btot) {
  __shared__ unsigned sd[256];
  const int bu = blockIdx.x, t = threadIdx.x;
  unsigned* base = (bu < NBUCK) ? histGd : histGs;
  const int b = (bu < NBUCK) ? bu : bu - NBUCK;
  unsigned v[4], s = 0;
  int jp[4];
#pragma unroll
  for (int i = 0; i < 4; ++i) {
    int q = t * 4 + i;
    jp[i] = (q & 7) * (NCHUNK / 8) + (q >> 3);  // XCD-grouped chunk order
    v[i] = (q < NCHUNK) ? base[(size_t)jp[i] * NBUCK + b] : 0u;
    s += v[i];
  }
  sd[t] = s;
  __syncthreads();
  for (int d = 1; d < 256; d <<= 1) {
    unsigned a = (t >= d) ? sd[t - d] : 0u;
    __syncthreads();
    sd[t] += a;
    __syncthreads();
  }
  unsigned run = sd[t] - s;
#pragma unroll
  for (int i = 0; i < 4; ++i) {
    int q = t * 4 + i;
    if (q < NCHUNK) { unsigned tv = v[i]; base[(size_t)jp[i] * NBUCK + b] = run; run += tv; }
  }
  if (t == 255) btot[bu] = run;
}

// two blocks: scan dst totals -> bbase, src totals -> sbase.
__global__ __launch_bounds__(1024) void k_bscan2(const unsigned* __restrict__ btot,
                                                 int* __restrict__ bbase,
                                                 int* __restrict__ sbase,
                                                 int* __restrict__ row_ptr) {
  __shared__ unsigned sd[1024];
  const int t = threadIdx.x;
  const unsigned* bt = btot + (blockIdx.x ? NBUCK : 0);
  int* ob = blockIdx.x ? sbase : bbase;
  unsigned v = (t < NBUCK) ? bt[t] : 0u;
  sd[t] = v;
  __syncthreads();
  for (int d = 1; d < 1024; d <<= 1) {
    unsigned a = (t >= d) ? sd[t - d] : 0u;
    __syncthreads();
    sd[t] += a;
    __syncthreads();
  }
  if (t < NBUCK) ob[t] = (int)(sd[t] - v);
  if (t == 0) {
    ob[NBUCK] = N_EDGES;
    if (blockIdx.x == 0) row_ptr[N_NODES] = N_EDGES;
  }
}

// scatter: dst stream packed (dst&127)<<17|src into ebuf; src residue byte into ebuf2.
__global__ __launch_bounds__(256) void k_part(const int* __restrict__ src,
                                              const int* __restrict__ dst,
                                              const unsigned* __restrict__ histGd,
                                              const unsigned* __restrict__ histGs,
                                              const int* __restrict__ bbase,
                                              const int* __restrict__ sbase,
                                              int* __restrict__ ebuf,
                                              unsigned char* __restrict__ ebuf2) {
  __shared__ unsigned lcD[NBUCK];
  __shared__ unsigned lcS[NBUCK];
  __shared__ int lbD[NBUCK];
  __shared__ int lbS[NBUCK];
  const int t = threadIdx.x, j = blockIdx.x;
  for (int i = t; i < NBUCK; i += 256) {
    lcD[i] = histGd[(size_t)j * NBUCK + i];
    lbD[i] = bbase[i];
    lcS[i] = histGs[(size_t)j * NBUCK + i];
    lbS[i] = sbase[i];
  }
  __syncthreads();
  const int e0 = j * CH;
  for (int e = e0 + t; e < e0 + CH; e += 256) {
    int d = dst[e], s = src[e];
    int bd = (unsigned)d >> BSHIFT;
    unsigned rd = atomicAdd(&lcD[bd], 1u);
    ebuf[lbD[bd] + (int)rd] = ((d & 127) << 17) | s;
    int bs = (unsigned)s >> BSHIFT;
    unsigned rs = atomicAdd(&lcS[bs], 1u);
    ebuf2[lbS[bs] + (int)rs] = (unsigned char)(s & 127);
  }
}

// Fused per-bucket pass: (A) src-degree -> oi (kept in LDS for coi);
// (B) dst counts -> row_ptr/ii/coi; (C) clustered csr_src fill.
__global__ __launch_bounds__(256) void k_buckets(const int* __restrict__ ebuf,
                                                 const unsigned char* __restrict__ ebuf2,
                                                 const int* __restrict__ bbase,
                                                 const int* __restrict__ sbase,
                                                 float* __restrict__ oi,
                                                 int* __restrict__ row_ptr,
                                                 int* __restrict__ csr_src,
                                                 float* __restrict__ ii,
                                                 float* __restrict__ coi) {
  __shared__ unsigned cntS[128];
  __shared__ unsigned cntD[128];
  __shared__ float oiL[128];
  __shared__ int start[128];
  const int b = blockIdx.x, t = threadIdx.x;
  const int node0 = b << BSHIFT;
  if (t < 128) { cntS[t] = 0u; cntD[t] = 0u; }
  __syncthreads();
  const int sbeg = sbase[b], send = sbase[b + 1];
  for (int j = sbeg + t; j < send; j += 256)
    atomicAdd(&cntS[ebuf2[j]], 1u);
  const int base = bbase[b], end = bbase[b + 1];
  for (int j = base + t; j < end; j += 256)
    atomicAdd(&cntD[(unsigned)ebuf[j] >> 17], 1u);
  __syncthreads();
  if (t < 128) {
    unsigned c = cntS[t]; if (c < 1u) c = 1u;
    float o = rsqrtf((float)c);
    oiL[t] = o;
    int n = node0 + t;
    if (n < N_NODES) oi[n] = o;
  }
  if (t == 0) {
    int r = 0;
    for (int i = 0; i < 128; ++i) { start[i] = r; r += (int)cntD[i]; }
  }
  __syncthreads();
  if (t < 128) {
    int n = node0 + t;
    if (n < N_NODES) {
      row_ptr[n] = base + start[t];
      unsigned c = cntD[t]; if (c < 1u) c = 1u;
      float iv = rsqrtf((float)c);
      ii[n] = iv;
      coi[n] = iv * oiL[t];  // relu(ii*agg)*oi == (ii*oi)*relu(agg)
    }
  }
  __syncthreads();
  if (t < 128) cntD[t] = (unsigned)start[t];  // reuse as cursors
  __syncthreads();
  for (int j = base + t; j < end; j += 256) {
    int pk = ebuf[j];
    unsigned dn = (unsigned)pk >> 17;
    unsigned slot = atomicAdd(&cntD[dn], 1u);
    csr_src[base + (int)slot] = pk & 0x1FFFF;
  }
}

// ---------------- GEMM1 (MFMA bf16): h1b = bf16((x*oi) @ W1), 100k x 128 x 128 ----------------
// B-fragments read straight from L2-hot Wt1 (no Ws LDS stage -> 17KB LDS, higher occupancy).

#define LPAD 136

__global__ __launch_bounds__(256) void k_gemm1(const float* __restrict__ x,
                                               const float* __restrict__ oi,
                                               const unsigned short* __restrict__ Wt1,
                                               unsigned short* __restrict__ h1b) {
  __shared__ unsigned short Xs[64 * LPAD];
  const int t = threadIdx.x;
  const int row0 = blockIdx.x * 64;
#pragma unroll
  for (int j = 0; j < 4; ++j) {
    int q = t + 256 * j;
    int r = q >> 4, c = q & 15;
    int gr = row0 + r; if (gr >= N_NODES) gr = N_NODES - 1;
    const float* xp = x + (size_t)gr * 128 + c * 8;
    float4 v0 = *(const float4*)(xp);
    float4 v1 = *(const float4*)(xp + 4);
    float s = oi[gr];
    uint4 pk;
    pk.x = pack_bf16x2(v0.x * s, v0.y * s);
    pk.y = pack_bf16x2(v0.z * s, v0.w * s);
    pk.z = pack_bf16x2(v1.x * s, v1.y * s);
    pk.w = pack_bf16x2(v1.z * s, v1.w * s);
    *(uint4*)(Xs + r * LPAD + c * 8) = pk;
  }
  __syncthreads();
  const int w = t >> 6, lane = t & 63;
  const int m = lane & 15;
  const int q8 = (lane >> 4) * 8;
  f32x4 acc[8];
#pragma unroll
  for (int i = 0; i < 8; ++i) acc[i] = (f32x4){0.f, 0.f, 0.f, 0.f};
  const unsigned short* xrow = Xs + (w * 16 + m) * LPAD;
  const unsigned short* wp = Wt1 + m * 128 + q8;
#pragma unroll
  for (int ks = 0; ks < 4; ++ks) {
    bf16x8 a = *(const bf16x8*)(xrow + ks * 32 + q8);
#pragma unroll
    for (int ct = 0; ct < 8; ++ct) {
      bf16x8 b = *(const bf16x8*)(wp + ct * 2048 + ks * 32);
      acc[ct] = __builtin_amdgcn_mfma_f32_16x16x32_bf16(a, b, acc[ct], 0, 0, 0);
    }
  }
  const int rbase = row0 + w * 16 + (lane >> 4) * 4;
#pragma unroll
  for (int ct = 0; ct < 8; ++ct) {
    int coln = ct * 16 + m;
#pragma unroll
    for (int r = 0; r < 4; ++r) {
      int grow = rbase + r;
      if (grow < N_NODES) h1b[(size_t)grow * 128 + coln] = bf16u(acc[ct][r]);
    }
  }
}

// ---------------- AGG1: g = bf16(coi * relu(sum h1[src]))  (16 lanes/node, uint4, MLP8) ----------------

__global__ __launch_bounds__(256) void k_agg1(const unsigned short* __restrict__ h1b,
                                              const int* __restrict__ csr_src,
                                              const int* __restrict__ row_ptr,
                                              const float* __restrict__ coi,
                                              unsigned short* __restrict__ g) {
  const int t = threadIdx.x;
  const int node = blockIdx.x * 16 + (t >> 4);
  const int c = t & 15;
  const int beg = row_ptr[node];
  const int end = row_ptr[node + 1];
  float4 a0 = make_float4(0.f, 0.f, 0.f, 0.f);
  float4 a1 = make_float4(0.f, 0.f, 0.f, 0.f);
  int j = beg;
  for (; j + 8 <= end; j += 8) {
    uint4 v[8];
#pragma unroll
    for (int i = 0; i < 8; ++i) {
      int s = csr_src[j + i];
      v[i] = *(const uint4*)(h1b + (size_t)s * 128 + 8 * c);
    }
#pragma unroll
    for (int i = 0; i < 8; ++i) {
      a0.x += bf_lo(v[i].x); a0.y += bf_hi(v[i].x);
      a0.z += bf_lo(v[i].y); a0.w += bf_hi(v[i].y);
      a1.x += bf_lo(v[i].z); a1.y += bf_hi(v[i].z);
      a1.z += bf_lo(v[i].w); a1.w += bf_hi(v[i].w);
    }
  }
  for (; j < end; ++j) {
    int s = csr_src[j];
    uint4 v = *(const uint4*)(h1b + (size_t)s * 128 + 8 * c);
    a0.x += bf_lo(v.x); a0.y += bf_hi(v.x); a0.z += bf_lo(v.y); a0.w += bf_hi(v.y);
    a1.x += bf_lo(v.z); a1.y += bf_hi(v.z); a1.z += bf_lo(v.w); a1.w += bf_hi(v.w);
  }
  float sc = coi[node];
  uint4 pk;
  pk.x = pack_bf16x2(fmaxf(a0.x, 0.f) * sc, fmaxf(a0.y, 0.f) * sc);
  pk.y = pack_bf16x2(fmaxf(a0.z, 0.f) * sc, fmaxf(a0.w, 0.f) * sc);
  pk.z = pack_bf16x2(fmaxf(a1.x, 0.f) * sc, fmaxf(a1.y, 0.f) * sc);
  pk.w = pack_bf16x2(fmaxf(a1.z, 0.f) * sc, fmaxf(a1.w, 0.f) * sc);
  *(uint4*)(g + (size_t)node * 128 + 8 * c) = pk;
}

// ---------------- GEMM2 (MFMA bf16): h2b = bf16(g @ W2), 100k x 128 x 40 (N pad 48) ----------------

__global__ __launch_bounds__(256) void k_gemm2(const unsigned short* __restrict__ gb,
                                               const unsigned short* __restrict__ Wt2,
                                               unsigned short* __restrict__ h2b) {
  __shared__ unsigned short Gs[64 * LPAD];
  __shared__ unsigned short Ws[48 * LPAD];
  const int t = threadIdx.x;
  const int row0 = blockIdx.x * 64;
#pragma unroll
  for (int j = 0; j < 3; ++j) {
    int q = t + 256 * j;
    int n = q >> 4, c = q & 15;
    *(uint4*)(Ws + n * LPAD + c * 8) = *(const uint4*)(Wt2 + n * 128 + c * 8);
  }
#pragma unroll
  for (int j = 0; j < 4; ++j) {
    int q = t + 256 * j;
    int r = q >> 4, c = q & 15;
    int gr = row0 + r; if (gr >= N_NODES) gr = N_NODES - 1;
    *(uint4*)(Gs + r * LPAD + c * 8) = *(const uint4*)(gb + (size_t)gr * 128 + c * 8);
  }
  __syncthreads();
  const int w = t >> 6, lane = t & 63;
  const int m = lane & 15;
  const int q8 = (lane >> 4) * 8;
  f32x4 acc[3];
#pragma unroll
  for (int i = 0; i < 3; ++i) acc[i] = (f32x4){0.f, 0.f, 0.f, 0.f};
  const unsigned short* grow_p = Gs + (w * 16 + m) * LPAD;
#pragma unroll
  for (int ks = 0; ks < 4; ++ks) {
    bf16x8 a = *(const bf16x8*)(grow_p + ks * 32 + q8);
#pragma unroll
    for (int ct = 0; ct < 3; ++ct) {
      bf16x8 b = *(const bf16x8*)(Ws + (ct * 16 + m) * LPAD + ks * 32 + q8);
      acc[ct] = __builtin_amdgcn_mfma_f32_16x16x32_bf16(a, b, acc[ct], 0, 0, 0);
    }
  }
  const int rbase = row0 + w * 16 + (lane >> 4) * 4;
#pragma unroll
  for (int ct = 0; ct < 3; ++ct) {
    int coln = ct * 16 + m;
    if (coln < 40) {
#pragma unroll
      for (int r = 0; r < 4; ++r) {
        int grow = rbase + r;
        if (grow < N_NODES) h2b[(size_t)grow * 40 + coln] = bf16u(acc[ct][r]);
      }
    }
  }
}

// ---------------- AGG2: out = ii * sum h2[src]  (16-lane groups, uint2, MLP8) ----------------

__global__ __launch_bounds__(256) void k_agg2(const unsigned short* __restrict__ h2b,
                                              const int* __restrict__ csr_src,
                                              const int* __restrict__ row_ptr,
                                              const float* __restrict__ ii,
                                              float* __restrict__ out) {
  const int t = threadIdx.x;
  const int node = blockIdx.x * 16 + (t >> 4);
  const int c = t & 15;
  if (c >= 10) return;
  const int beg = row_ptr[node];
  const int end = row_ptr[node + 1];
  float4 acc = make_float4(0.f, 0.f, 0.f, 0.f);
  int j = beg;
  for (; j + 8 <= end; j += 8) {
    uint2 v[8];
#pragma unroll
    for (int i = 0; i < 8; ++i) {
      int s = csr_src[j + i];
      v[i] = *(const uint2*)(h2b + (size_t)s * 40 + 4 * c);
    }
#pragma unroll
    for (int i = 0; i < 8; ++i) {
      acc.x += bf_lo(v[i].x); acc.y += bf_hi(v[i].x);
      acc.z += bf_lo(v[i].y); acc.w += bf_hi(v[i].y);
    }
  }
  for (; j < end; ++j) {
    int s = csr_src[j];
    uint2 v = *(const uint2*)(h2b + (size_t)s * 40 + 4 * c);
    acc.x += bf_lo(v.x); acc.y += bf_hi(v.x); acc.z += bf_lo(v.y); acc.w += bf_hi(v.y);
  }
  float sc = ii[node];
  acc.x *= sc; acc.y *= sc; acc.z *= sc; acc.w *= sc;
  *(float4*)(out + (size_t)node * 40 + 4 * c) = acc;
}

// ---------------- launch ----------------

extern "C" void kernel_launch(void* const* d_in, const int* in_sizes, int n_in,
                              void* d_out, int out_size, void* d_ws, size_t ws_size,
                              hipStream_t stream) {
  const float* x  = (const float*)d_in[0];
  const int* ei   = (const int*)d_in[1];
  const float* W1 = (const float*)d_in[2];
  const float* W2 = (const float*)d_in[3];
  const int* src = ei;
  const int* dst = ei + N_EDGES;
  float* out = (float*)d_out;

  char* p = (char*)d_ws;
  auto alloc = [&](size_t b) -> void* {
    char* r = p;
    p += (b + 255) & ~(size_t)255;
    return (void*)r;
  };
  float* oi             = (float*)alloc((size_t)N_NODES * 4);
  float* ii             = (float*)alloc((size_t)N_NODES * 4);
  float* coi            = (float*)alloc((size_t)N_NODES * 4);
  int* row_ptr          = (int*)alloc((size_t)(N_NODES + 1) * 4);
  unsigned* histGd      = (unsigned*)alloc((size_t)NBUCK * NCHUNK * 4);
  unsigned* histGs      = (unsigned*)alloc((size_t)NBUCK * NCHUNK * 4);
  unsigned* btot        = (unsigned*)alloc((size_t)2 * NBUCK * 4);
  int* bbase            = (int*)alloc((size_t)(NBUCK + 1) * 4);
  int* sbase            = (int*)alloc((size_t)(NBUCK + 1) * 4);
  int* ebuf             = (int*)alloc((size_t)N_EDGES * 4);
  unsigned char* ebuf2  = (unsigned char*)alloc((size_t)N_EDGES);
  int* csr_src          = (int*)alloc((size_t)N_EDGES * 4);
  unsigned short* Wt1   = (unsigned short*)alloc((size_t)128 * 128 * 2);
  unsigned short* Wt2   = (unsigned short*)alloc((size_t)48 * 128 * 2);
  unsigned short* h1b   = (unsigned short*)alloc((size_t)N_NODES * 128 * 2);
  unsigned short* g     = (unsigned short*)alloc((size_t)N_NODES * 128 * 2);
  unsigned short* h2b   = (unsigned short*)alloc((size_t)N_NODES * 40 * 2);

  k_prepw<<<64, 256, 0, stream>>>(W1, W2, Wt1, Wt2);
  k_hist<<<NCHUNK, 256, 0, stream>>>(src, dst, histGd, histGs);
  k_offs<<<2 * NBUCK, 256, 0, stream>>>(histGd, histGs, btot);
  k_bscan2<<<2, 1024, 0, stream>>>(btot, bbase, sbase, row_ptr);
  k_part<<<NCHUNK, 256, 0, stream>>>(src, dst, histGd, histGs, bbase, sbase, ebuf, ebuf2);
  k_buckets<<<NBUCK, 256, 0, stream>>>(ebuf, ebuf2, bbase, sbase, oi, row_ptr, csr_src,
                                       ii, coi);
  k_gemm1<<<(N_NODES + 63) / 64, 256, 0, stream>>>(x, oi, Wt1, h1b);
  k_agg1<<<N_NODES / 16, 256, 0, stream>>>(h1b, csr_src, row_ptr, coi, g);
  k_gemm2<<<(N_NODES + 63) / 64, 256, 0, stream>>>(g, Wt2, h2b);
  k_agg2<<<N_NODES / 16, 256, 0, stream>>>(h2b, csr_src, row_ptr, ii, out);
}

// Round 10
// 284.316 us; speedup vs baseline: 1.1171x; 1.1171x over previous
//
#include <hip/hip_runtime.h>

#define N_NODES 100000
#define N_EDGES 1600000
#define BSHIFT 7
#define NBUCK 782     // ceil(N_NODES/128)
#define NCHUNK 1000
#define CH 1600       // N_EDGES / NCHUNK exactly

typedef __attribute__((ext_vector_type(8))) short bf16x8;
typedef __attribute__((ext_vector_type(4))) float f32x4;

// bf16 helpers (RTNE pack; unpack = shift to high half)
__device__ __forceinline__ unsigned pack_bf16x2(float a, float b) {
  unsigned ua = __float_as_uint(a);
  unsigned ub = __float_as_uint(b);
  ua = ua + 0x7fffu + ((ua >> 16) & 1u);
  ub = ub + 0x7fffu + ((ub >> 16) & 1u);
  return (ua >> 16) | (ub & 0xffff0000u);
}
__device__ __forceinline__ unsigned short bf16u(float f) {
  unsigned u = __float_as_uint(f);
  u = u + 0x7fffu + ((u >> 16) & 1u);
  return (unsigned short)(u >> 16);
}
__device__ __forceinline__ float bf_lo(unsigned u) { return __uint_as_float(u << 16); }
__device__ __forceinline__ float bf_hi(unsigned u) { return __uint_as_float(u & 0xffff0000u); }

// ---------------- counting-sort partition (histG layout [bucket][chunk], round-8 proven) ----
// k_hist also hosts the one-shot weight transpose in its first 64 blocks.

__global__ __launch_bounds__(256) void k_hist(const int* __restrict__ src,
                                              const int* __restrict__ dst,
                                              unsigned* __restrict__ histGd,
                                              unsigned* __restrict__ histGs,
                                              const float* __restrict__ W1,
                                              const float* __restrict__ W2,
                                              unsigned short* __restrict__ Wt1,
                                              unsigned short* __restrict__ Wt2) {
  __shared__ unsigned hd[NBUCK];
  __shared__ unsigned hs[NBUCK];
  const int t = threadIdx.x, j = blockIdx.x;
  if (j < 64) {  // fused weight prep (once)
    int q = j * 256 + t;
    {
      int n = q >> 7, k = q & 127;
      Wt1[n * 128 + k] = bf16u(W1[k * 128 + n]);
    }
    if (q < 48 * 128) {
      int n = q >> 7, k = q & 127;
      float v = (n < 40) ? W2[k * 40 + n] : 0.f;
      Wt2[n * 128 + k] = bf16u(v);
    }
  }
  for (int i = t; i < NBUCK; i += 256) { hd[i] = 0u; hs[i] = 0u; }
  __syncthreads();
  const int e0 = j * CH;
  for (int e = e0 + t; e < e0 + CH; e += 256) {
    atomicAdd(&hd[(unsigned)dst[e] >> BSHIFT], 1u);
    atomicAdd(&hs[(unsigned)src[e] >> BSHIFT], 1u);
  }
  __syncthreads();
  for (int i = t; i < NBUCK; i += 256) {
    histGd[(size_t)i * NCHUNK + j] = hd[i];
    histGs[(size_t)i * NCHUNK + j] = hs[i];
  }
}

// block per (bucket, stream): exclusive scan of NCHUNK chunk-counts in place + total.
__global__ __launch_bounds__(256) void k_offs(unsigned* __restrict__ histGd,
                                              unsigned* __restrict__ histGs,
                                              unsigned* __restrict__ btot) {
  __shared__ unsigned sd[256];
  const int bu = blockIdx.x, t = threadIdx.x;
  unsigned* col = (bu < NBUCK) ? histGd + (size_t)bu * NCHUNK
                               : histGs + (size_t)(bu - NBUCK) * NCHUNK;
  unsigned v[4], s = 0;
#pragma unroll
  for (int i = 0; i < 4; ++i) {
    int idx = t * 4 + i;
    v[i] = (idx < NCHUNK) ? col[idx] : 0u;
    s += v[i];
  }
  sd[t] = s;
  __syncthreads();
  for (int d = 1; d < 256; d <<= 1) {
    unsigned a = (t >= d) ? sd[t - d] : 0u;
    __syncthreads();
    sd[t] += a;
    __syncthreads();
  }
  unsigned run = sd[t] - s;
#pragma unroll
  for (int i = 0; i < 4; ++i) {
    int idx = t * 4 + i;
    if (idx < NCHUNK) { unsigned tv = v[i]; col[idx] = run; run += tv; }
  }
  if (t == 255) btot[bu] = run;
}

// two blocks: scan dst totals -> bbase, src totals -> sbase.
__global__ __launch_bounds__(1024) void k_bscan2(const unsigned* __restrict__ btot,
                                                 int* __restrict__ bbase,
                                                 int* __restrict__ sbase,
                                                 int* __restrict__ row_ptr) {
  __shared__ unsigned sd[1024];
  const int t = threadIdx.x;
  const unsigned* bt = btot + (blockIdx.x ? NBUCK : 0);
  int* ob = blockIdx.x ? sbase : bbase;
  unsigned v = (t < NBUCK) ? bt[t] : 0u;
  sd[t] = v;
  __syncthreads();
  for (int d = 1; d < 1024; d <<= 1) {
    unsigned a = (t >= d) ? sd[t - d] : 0u;
    __syncthreads();
    sd[t] += a;
    __syncthreads();
  }
  if (t < NBUCK) ob[t] = (int)(sd[t] - v);
  if (t == 0) {
    ob[NBUCK] = N_EDGES;
    if (blockIdx.x == 0) row_ptr[N_NODES] = N_EDGES;
  }
}

// scatter: dst stream packed (dst&127)<<17|src into ebuf; src residue byte into ebuf2.
__global__ __launch_bounds__(256) void k_part(const int* __restrict__ src,
                                              const int* __restrict__ dst,
                                              const unsigned* __restrict__ histGd,
                                              const unsigned* __restrict__ histGs,
                                              const int* __restrict__ bbase,
                                              const int* __restrict__ sbase,
                                              int* __restrict__ ebuf,
                                              unsigned char* __restrict__ ebuf2) {
  __shared__ unsigned lcD[NBUCK];
  __shared__ unsigned lcS[NBUCK];
  __shared__ int lbD[NBUCK];
  __shared__ int lbS[NBUCK];
  const int t = threadIdx.x, j = blockIdx.x;
  for (int i = t; i < NBUCK; i += 256) {
    lcD[i] = histGd[(size_t)i * NCHUNK + j];
    lbD[i] = bbase[i];
    lcS[i] = histGs[(size_t)i * NCHUNK + j];
    lbS[i] = sbase[i];
  }
  __syncthreads();
  const int e0 = j * CH;
  for (int e = e0 + t; e < e0 + CH; e += 256) {
    int d = dst[e], s = src[e];
    int bd = (unsigned)d >> BSHIFT;
    unsigned rd = atomicAdd(&lcD[bd], 1u);
    ebuf[lbD[bd] + (int)rd] = ((d & 127) << 17) | s;
    int bs = (unsigned)s >> BSHIFT;
    unsigned rs = atomicAdd(&lcS[bs], 1u);
    ebuf2[lbS[bs] + (int)rs] = (unsigned char)(s & 127);
  }
}

// Fused per-bucket pass: (A) src-degree -> oi (kept in LDS for coi);
// (B) dst counts -> row_ptr/ii/coi (parallel 128-scan); (C) clustered csr_src fill.
__global__ __launch_bounds__(256) void k_buckets(const int* __restrict__ ebuf,
                                                 const unsigned char* __restrict__ ebuf2,
                                                 const int* __restrict__ bbase,
                                                 const int* __restrict__ sbase,
                                                 float* __restrict__ oi,
                                                 int* __restrict__ row_ptr,
                                                 int* __restrict__ csr_src,
                                                 float* __restrict__ ii,
                                                 float* __restrict__ coi) {
  __shared__ unsigned cntS[128];
  __shared__ unsigned cntD[128];
  __shared__ float oiL[128];
  __shared__ unsigned sc2[128];
  const int b = blockIdx.x, t = threadIdx.x;
  const int node0 = b << BSHIFT;
  if (t < 128) { cntS[t] = 0u; cntD[t] = 0u; }
  __syncthreads();
  const int sbeg = sbase[b], send = sbase[b + 1];
  for (int j = sbeg + t; j < send; j += 256)
    atomicAdd(&cntS[ebuf2[j]], 1u);
  const int base = bbase[b], end = bbase[b + 1];
  for (int j = base + t; j < end; j += 256)
    atomicAdd(&cntD[(unsigned)ebuf[j] >> 17], 1u);
  __syncthreads();
  unsigned cD = (t < 128) ? cntD[t] : 0u;
  if (t < 128) sc2[t] = cD;
  __syncthreads();
  for (int d = 1; d < 128; d <<= 1) {
    unsigned a = (t < 128 && t >= d) ? sc2[t - d] : 0u;
    __syncthreads();
    if (t < 128) sc2[t] += a;
    __syncthreads();
  }
  if (t < 128) {
    unsigned ex = sc2[t] - cD;  // exclusive prefix
    unsigned cs = cntS[t]; if (cs < 1u) cs = 1u;
    float o = rsqrtf((float)cs);
    oiL[t] = o;
    int n = node0 + t;
    if (n < N_NODES) {
      oi[n] = o;
      row_ptr[n] = base + (int)ex;
      unsigned c = cD; if (c < 1u) c = 1u;
      float iv = rsqrtf((float)c);
      ii[n] = iv;
      coi[n] = iv * o;  // relu(ii*agg)*oi == (ii*oi)*relu(agg)
    }
    cntD[t] = ex;  // reuse as cursors
  }
  __syncthreads();
  for (int j = base + t; j < end; j += 256) {
    int pk = ebuf[j];
    unsigned dn = (unsigned)pk >> 17;
    unsigned slot = atomicAdd(&cntD[dn], 1u);
    csr_src[base + (int)slot] = pk & 0x1FFFF;
  }
}

// ---------------- GEMM1 (MFMA bf16): h1b = bf16((x*oi) @ W1), 100k x 128 x 128 ----------------

#define LPAD 136

__global__ __launch_bounds__(256) void k_gemm1(const float* __restrict__ x,
                                               const float* __restrict__ oi,
                                               const unsigned short* __restrict__ Wt1,
                                               unsigned short* __restrict__ h1b) {
  __shared__ unsigned short Xs[64 * LPAD];
  __shared__ unsigned short Ws[128 * LPAD];
  const int t = threadIdx.x;
  const int row0 = blockIdx.x * 64;
#pragma unroll
  for (int j = 0; j < 8; ++j) {
    int q = t + 256 * j;
    int n = q >> 4, c = q & 15;
    *(uint4*)(Ws + n * LPAD + c * 8) = *(const uint4*)(Wt1 + n * 128 + c * 8);
  }
#pragma unroll
  for (int j = 0; j < 4; ++j) {
    int q = t + 256 * j;
    int r = q >> 4, c = q & 15;
    int gr = row0 + r; if (gr >= N_NODES) gr = N_NODES - 1;
    const float* xp = x + (size_t)gr * 128 + c * 8;
    float4 v0 = *(const float4*)(xp);
    float4 v1 = *(const float4*)(xp + 4);
    float s = oi[gr];
    uint4 pk;
    pk.x = pack_bf16x2(v0.x * s, v0.y * s);
    pk.y = pack_bf16x2(v0.z * s, v0.w * s);
    pk.z = pack_bf16x2(v1.x * s, v1.y * s);
    pk.w = pack_bf16x2(v1.z * s, v1.w * s);
    *(uint4*)(Xs + r * LPAD + c * 8) = pk;
  }
  __syncthreads();
  const int w = t >> 6, lane = t & 63;
  const int m = lane & 15;
  const int q8 = (lane >> 4) * 8;
  f32x4 acc[8];
#pragma unroll
  for (int i = 0; i < 8; ++i) acc[i] = (f32x4){0.f, 0.f, 0.f, 0.f};
  const unsigned short* xrow = Xs + (w * 16 + m) * LPAD;
#pragma unroll
  for (int ks = 0; ks < 4; ++ks) {
    bf16x8 a = *(const bf16x8*)(xrow + ks * 32 + q8);
#pragma unroll
    for (int ct = 0; ct < 8; ++ct) {
      bf16x8 b = *(const bf16x8*)(Ws + (ct * 16 + m) * LPAD + ks * 32 + q8);
      acc[ct] = __builtin_amdgcn_mfma_f32_16x16x32_bf16(a, b, acc[ct], 0, 0, 0);
    }
  }
  const int rbase = row0 + w * 16 + (lane >> 4) * 4;
#pragma unroll
  for (int ct = 0; ct < 8; ++ct) {
    int coln = ct * 16 + m;
#pragma unroll
    for (int r = 0; r < 4; ++r) {
      int grow = rbase + r;
      if (grow < N_NODES) h1b[(size_t)grow * 128 + coln] = bf16u(acc[ct][r]);
    }
  }
}

// ---------------- AGG1: g = bf16(coi * relu(sum h1[src]))  (16 lanes/node, uint4, MLP 8/4/1) ----

__global__ __launch_bounds__(256) void k_agg1(const unsigned short* __restrict__ h1b,
                                              const int* __restrict__ csr_src,
                                              const int* __restrict__ row_ptr,
                                              const float* __restrict__ coi,
                                              unsigned short* __restrict__ g) {
  const int t = threadIdx.x;
  const int node = blockIdx.x * 16 + (t >> 4);
  const int c = t & 15;
  const int beg = row_ptr[node];
  const int end = row_ptr[node + 1];
  float4 a0 = make_float4(0.f, 0.f, 0.f, 0.f);
  float4 a1 = make_float4(0.f, 0.f, 0.f, 0.f);
  int j = beg;
  for (; j + 8 <= end; j += 8) {
    uint4 v[8];
#pragma unroll
    for (int i = 0; i < 8; ++i) {
      int s = csr_src[j + i];
      v[i] = *(const uint4*)(h1b + (size_t)s * 128 + 8 * c);
    }
#pragma unroll
    for (int i = 0; i < 8; ++i) {
      a0.x += bf_lo(v[i].x); a0.y += bf_hi(v[i].x);
      a0.z += bf_lo(v[i].y); a0.w += bf_hi(v[i].y);
      a1.x += bf_lo(v[i].z); a1.y += bf_hi(v[i].z);
      a1.z += bf_lo(v[i].w); a1.w += bf_hi(v[i].w);
    }
  }
  if (j + 4 <= end) {
    uint4 v[4];
#pragma unroll
    for (int i = 0; i < 4; ++i) {
      int s = csr_src[j + i];
      v[i] = *(const uint4*)(h1b + (size_t)s * 128 + 8 * c);
    }
#pragma unroll
    for (int i = 0; i < 4; ++i) {
      a0.x += bf_lo(v[i].x); a0.y += bf_hi(v[i].x);
      a0.z += bf_lo(v[i].y); a0.w += bf_hi(v[i].y);
      a1.x += bf_lo(v[i].z); a1.y += bf_hi(v[i].z);
      a1.z += bf_lo(v[i].w); a1.w += bf_hi(v[i].w);
    }
    j += 4;
  }
  for (; j < end; ++j) {
    int s = csr_src[j];
    uint4 v = *(const uint4*)(h1b + (size_t)s * 128 + 8 * c);
    a0.x += bf_lo(v.x); a0.y += bf_hi(v.x); a0.z += bf_lo(v.y); a0.w += bf_hi(v.y);
    a1.x += bf_lo(v.z); a1.y += bf_hi(v.z); a1.z += bf_lo(v.w); a1.w += bf_hi(v.w);
  }
  float sc = coi[node];
  uint4 pk;
  pk.x = pack_bf16x2(fmaxf(a0.x, 0.f) * sc, fmaxf(a0.y, 0.f) * sc);
  pk.y = pack_bf16x2(fmaxf(a0.z, 0.f) * sc, fmaxf(a0.w, 0.f) * sc);
  pk.z = pack_bf16x2(fmaxf(a1.x, 0.f) * sc, fmaxf(a1.y, 0.f) * sc);
  pk.w = pack_bf16x2(fmaxf(a1.z, 0.f) * sc, fmaxf(a1.w, 0.f) * sc);
  *(uint4*)(g + (size_t)node * 128 + 8 * c) = pk;
}

// ---------------- GEMM2 (MFMA bf16): h2b = bf16(g @ W2), 100k x 128 x 40 (N pad 48) ----------------

__global__ __launch_bounds__(256) void k_gemm2(const unsigned short* __restrict__ gb,
                                               const unsigned short* __restrict__ Wt2,
                                               unsigned short* __restrict__ h2b) {
  __shared__ unsigned short Gs[64 * LPAD];
  __shared__ unsigned short Ws[48 * LPAD];
  const int t = threadIdx.x;
  const int row0 = blockIdx.x * 64;
#pragma unroll
  for (int j = 0; j < 3; ++j) {
    int q = t + 256 * j;
    int n = q >> 4, c = q & 15;
    *(uint4*)(Ws + n * LPAD + c * 8) = *(const uint4*)(Wt2 + n * 128 + c * 8);
  }
#pragma unroll
  for (int j = 0; j < 4; ++j) {
    int q = t + 256 * j;
    int r = q >> 4, c = q & 15;
    int gr = row0 + r; if (gr >= N_NODES) gr = N_NODES - 1;
    *(uint4*)(Gs + r * LPAD + c * 8) = *(const uint4*)(gb + (size_t)gr * 128 + c * 8);
  }
  __syncthreads();
  const int w = t >> 6, lane = t & 63;
  const int m = lane & 15;
  const int q8 = (lane >> 4) * 8;
  f32x4 acc[3];
#pragma unroll
  for (int i = 0; i < 3; ++i) acc[i] = (f32x4){0.f, 0.f, 0.f, 0.f};
  const unsigned short* grow_p = Gs + (w * 16 + m) * LPAD;
#pragma unroll
  for (int ks = 0; ks < 4; ++ks) {
    bf16x8 a = *(const bf16x8*)(grow_p + ks * 32 + q8);
#pragma unroll
    for (int ct = 0; ct < 3; ++ct) {
      bf16x8 b = *(const bf16x8*)(Ws + (ct * 16 + m) * LPAD + ks * 32 + q8);
      acc[ct] = __builtin_amdgcn_mfma_f32_16x16x32_bf16(a, b, acc[ct], 0, 0, 0);
    }
  }
  const int rbase = row0 + w * 16 + (lane >> 4) * 4;
#pragma unroll
  for (int ct = 0; ct < 3; ++ct) {
    int coln = ct * 16 + m;
    if (coln < 40) {
#pragma unroll
      for (int r = 0; r < 4; ++r) {
        int grow = rbase + r;
        if (grow < N_NODES) h2b[(size_t)grow * 40 + coln] = bf16u(acc[ct][r]);
      }
    }
  }
}

// ---------------- AGG2: out = ii * sum h2[src]  (16-lane groups, uint2, MLP 8/4/1) ----------------

__global__ __launch_bounds__(256) void k_agg2(const unsigned short* __restrict__ h2b,
                                              const int* __restrict__ csr_src,
                                              const int* __restrict__ row_ptr,
                                              const float* __restrict__ ii,
                                              float* __restrict__ out) {
  const int t = threadIdx.x;
  const int node = blockIdx.x * 16 + (t >> 4);
  const int c = t & 15;
  if (c >= 10) return;
  const int beg = row_ptr[node];
  const int end = row_ptr[node + 1];
  float4 acc = make_float4(0.f, 0.f, 0.f, 0.f);
  int j = beg;
  for (; j + 8 <= end; j += 8) {
    uint2 v[8];
#pragma unroll
    for (int i = 0; i < 8; ++i) {
      int s = csr_src[j + i];
      v[i] = *(const uint2*)(h2b + (size_t)s * 40 + 4 * c);
    }
#pragma unroll
    for (int i = 0; i < 8; ++i) {
      acc.x += bf_lo(v[i].x); acc.y += bf_hi(v[i].x);
      acc.z += bf_lo(v[i].y); acc.w += bf_hi(v[i].y);
    }
  }
  if (j + 4 <= end) {
    uint2 v[4];
#pragma unroll
    for (int i = 0; i < 4; ++i) {
      int s = csr_src[j + i];
      v[i] = *(const uint2*)(h2b + (size_t)s * 40 + 4 * c);
    }
#pragma unroll
    for (int i = 0; i < 4; ++i) {
      acc.x += bf_lo(v[i].x); acc.y += bf_hi(v[i].x);
      acc.z += bf_lo(v[i].y); acc.w += bf_hi(v[i].y);
    }
    j += 4;
  }
  for (; j < end; ++j) {
    int s = csr_src[j];
    uint2 v = *(const uint2*)(h2b + (size_t)s * 40 + 4 * c);
    acc.x += bf_lo(v.x); acc.y += bf_hi(v.x); acc.z += bf_lo(v.y); acc.w += bf_hi(v.y);
  }
  float sc = ii[node];
  acc.x *= sc; acc.y *= sc; acc.z *= sc; acc.w *= sc;
  *(float4*)(out + (size_t)node * 40 + 4 * c) = acc;
}

// ---------------- launch ----------------

extern "C" void kernel_launch(void* const* d_in, const int* in_sizes, int n_in,
                              void* d_out, int out_size, void* d_ws, size_t ws_size,
                              hipStream_t stream) {
  const float* x  = (const float*)d_in[0];
  const int* ei   = (const int*)d_in[1];
  const float* W1 = (const float*)d_in[2];
  const float* W2 = (const float*)d_in[3];
  const int* src = ei;
  const int* dst = ei + N_EDGES;
  float* out = (float*)d_out;

  char* p = (char*)d_ws;
  auto alloc = [&](size_t b) -> void* {
    char* r = p;
    p += (b + 255) & ~(size_t)255;
    return (void*)r;
  };
  float* oi             = (float*)alloc((size_t)N_NODES * 4);
  float* ii             = (float*)alloc((size_t)N_NODES * 4);
  float* coi            = (float*)alloc((size_t)N_NODES * 4);
  int* row_ptr          = (int*)alloc((size_t)(N_NODES + 1) * 4);
  unsigned* histGd      = (unsigned*)alloc((size_t)NBUCK * NCHUNK * 4);
  unsigned* histGs      = (unsigned*)alloc((size_t)NBUCK * NCHUNK * 4);
  unsigned* btot        = (unsigned*)alloc((size_t)2 * NBUCK * 4);
  int* bbase            = (int*)alloc((size_t)(NBUCK + 1) * 4);
  int* sbase            = (int*)alloc((size_t)(NBUCK + 1) * 4);
  int* ebuf             = (int*)alloc((size_t)N_EDGES * 4);
  unsigned char* ebuf2  = (unsigned char*)alloc((size_t)N_EDGES);
  int* csr_src          = (int*)alloc((size_t)N_EDGES * 4);
  unsigned short* Wt1   = (unsigned short*)alloc((size_t)128 * 128 * 2);
  unsigned short* Wt2   = (unsigned short*)alloc((size_t)48 * 128 * 2);
  unsigned short* h1b   = (unsigned short*)alloc((size_t)N_NODES * 128 * 2);
  unsigned short* g     = (unsigned short*)alloc((size_t)N_NODES * 128 * 2);
  unsigned short* h2b   = (unsigned short*)alloc((size_t)N_NODES * 40 * 2);

  k_hist<<<NCHUNK, 256, 0, stream>>>(src, dst, histGd, histGs, W1, W2, Wt1, Wt2);
  k_offs<<<2 * NBUCK, 256, 0, stream>>>(histGd, histGs, btot);
  k_bscan2<<<2, 1024, 0, stream>>>(btot, bbase, sbase, row_ptr);
  k_part<<<NCHUNK, 256, 0, stream>>>(src, dst, histGd, histGs, bbase, sbase, ebuf, ebuf2);
  k_buckets<<<NBUCK, 256, 0, stream>>>(ebuf, ebuf2, bbase, sbase, oi, row_ptr, csr_src,
                                       ii, coi);
  k_gemm1<<<(N_NODES + 63) / 64, 256, 0, stream>>>(x, oi, Wt1, h1b);
  k_agg1<<<N_NODES / 16, 256, 0, stream>>>(h1b, csr_src, row_ptr, coi, g);
  k_gemm2<<<(N_NODES + 63) / 64, 256, 0, stream>>>(g, Wt2, h2b);
  k_agg2<<<N_NODES / 16, 256, 0, stream>>>(h2b, csr_src, row_ptr, ii, out);
}

// Round 11
// 277.720 us; speedup vs baseline: 1.1437x; 1.0237x over previous
//
#include <hip/hip_runtime.h>

#define N_NODES 100000
#define N_EDGES 1600000
#define BSHIFT 7
#define NBUCK 782     // ceil(N_NODES/128)
#define NCHUNK 500
#define CH 3200       // N_EDGES / NCHUNK exactly

typedef __attribute__((ext_vector_type(8))) short bf16x8;
typedef __attribute__((ext_vector_type(4))) float f32x4;

// bf16 helpers (RTNE pack; unpack = shift to high half)
__device__ __forceinline__ unsigned pack_bf16x2(float a, float b) {
  unsigned ua = __float_as_uint(a);
  unsigned ub = __float_as_uint(b);
  ua = ua + 0x7fffu + ((ua >> 16) & 1u);
  ub = ub + 0x7fffu + ((ub >> 16) & 1u);
  return (ua >> 16) | (ub & 0xffff0000u);
}
__device__ __forceinline__ unsigned short bf16u(float f) {
  unsigned u = __float_as_uint(f);
  u = u + 0x7fffu + ((u >> 16) & 1u);
  return (unsigned short)(u >> 16);
}
__device__ __forceinline__ float bf_lo(unsigned u) { return __uint_as_float(u << 16); }
__device__ __forceinline__ float bf_hi(unsigned u) { return __uint_as_float(u & 0xffff0000u); }

// ---------------- counting-sort partition (histG [bucket][chunk]; fused weight prep) -------

__global__ __launch_bounds__(256) void k_hist(const int* __restrict__ src,
                                              const int* __restrict__ dst,
                                              unsigned* __restrict__ histGd,
                                              unsigned* __restrict__ histGs,
                                              const float* __restrict__ W1,
                                              const float* __restrict__ W2,
                                              unsigned short* __restrict__ Wt1,
                                              unsigned short* __restrict__ Wt2) {
  __shared__ unsigned hd[NBUCK];
  __shared__ unsigned hs[NBUCK];
  const int t = threadIdx.x, j = blockIdx.x;
  if (j < 64) {  // fused weight prep (once)
    int q = j * 256 + t;
    {
      int n = q >> 7, k = q & 127;
      Wt1[n * 128 + k] = bf16u(W1[k * 128 + n]);
    }
    if (q < 48 * 128) {
      int n = q >> 7, k = q & 127;
      float v = (n < 40) ? W2[k * 40 + n] : 0.f;
      Wt2[n * 128 + k] = bf16u(v);
    }
  }
  for (int i = t; i < NBUCK; i += 256) { hd[i] = 0u; hs[i] = 0u; }
  __syncthreads();
  const int e0 = j * CH;
  for (int e = e0 + t; e < e0 + CH; e += 256) {
    atomicAdd(&hd[(unsigned)dst[e] >> BSHIFT], 1u);
    atomicAdd(&hs[(unsigned)src[e] >> BSHIFT], 1u);
  }
  __syncthreads();
  for (int i = t; i < NBUCK; i += 256) {
    histGd[(size_t)i * NCHUNK + j] = hd[i];
    histGs[(size_t)i * NCHUNK + j] = hs[i];
  }
}

// block per (bucket, stream): exclusive scan of NCHUNK chunk-counts in place + total.
__global__ __launch_bounds__(256) void k_offs(unsigned* __restrict__ histGd,
                                              unsigned* __restrict__ histGs,
                                              unsigned* __restrict__ btot) {
  __shared__ unsigned sd[256];
  const int bu = blockIdx.x, t = threadIdx.x;
  unsigned* col = (bu < NBUCK) ? histGd + (size_t)bu * NCHUNK
                               : histGs + (size_t)(bu - NBUCK) * NCHUNK;
  unsigned v[2], s = 0;
#pragma unroll
  for (int i = 0; i < 2; ++i) {
    int idx = t * 2 + i;
    v[i] = (idx < NCHUNK) ? col[idx] : 0u;
    s += v[i];
  }
  sd[t] = s;
  __syncthreads();
  for (int d = 1; d < 256; d <<= 1) {
    unsigned a = (t >= d) ? sd[t - d] : 0u;
    __syncthreads();
    sd[t] += a;
    __syncthreads();
  }
  unsigned run = sd[t] - s;
#pragma unroll
  for (int i = 0; i < 2; ++i) {
    int idx = t * 2 + i;
    if (idx < NCHUNK) { unsigned tv = v[i]; col[idx] = run; run += tv; }
  }
  if (t == 255) btot[bu] = run;
}

// two blocks: scan dst totals -> bbase, src totals -> sbase.
__global__ __launch_bounds__(1024) void k_bscan2(const unsigned* __restrict__ btot,
                                                 int* __restrict__ bbase,
                                                 int* __restrict__ sbase,
                                                 int* __restrict__ row_ptr) {
  __shared__ unsigned sd[1024];
  const int t = threadIdx.x;
  const unsigned* bt = btot + (blockIdx.x ? NBUCK : 0);
  int* ob = blockIdx.x ? sbase : bbase;
  unsigned v = (t < NBUCK) ? bt[t] : 0u;
  sd[t] = v;
  __syncthreads();
  for (int d = 1; d < 1024; d <<= 1) {
    unsigned a = (t >= d) ? sd[t - d] : 0u;
    __syncthreads();
    sd[t] += a;
    __syncthreads();
  }
  if (t < NBUCK) ob[t] = (int)(sd[t] - v);
  if (t == 0) {
    ob[NBUCK] = N_EDGES;
    if (blockIdx.x == 0) row_ptr[N_NODES] = N_EDGES;
  }
}

// scatter: dst stream packed (dst&127)<<17|src into ebuf; src residue byte into ebuf2.
__global__ __launch_bounds__(256) void k_part(const int* __restrict__ src,
                                              const int* __restrict__ dst,
                                              const unsigned* __restrict__ histGd,
                                              const unsigned* __restrict__ histGs,
                                              const int* __restrict__ bbase,
                                              const int* __restrict__ sbase,
                                              int* __restrict__ ebuf,
                                              unsigned char* __restrict__ ebuf2) {
  __shared__ unsigned lcD[NBUCK];
  __shared__ unsigned lcS[NBUCK];
  __shared__ int lbD[NBUCK];
  __shared__ int lbS[NBUCK];
  const int t = threadIdx.x, j = blockIdx.x;
  for (int i = t; i < NBUCK; i += 256) {
    lcD[i] = histGd[(size_t)i * NCHUNK + j];
    lbD[i] = bbase[i];
    lcS[i] = histGs[(size_t)i * NCHUNK + j];
    lbS[i] = sbase[i];
  }
  __syncthreads();
  const int e0 = j * CH;
  for (int e = e0 + t; e < e0 + CH; e += 256) {
    int d = dst[e], s = src[e];
    int bd = (unsigned)d >> BSHIFT;
    unsigned rd = atomicAdd(&lcD[bd], 1u);
    ebuf[lbD[bd] + (int)rd] = ((d & 127) << 17) | s;
    int bs = (unsigned)s >> BSHIFT;
    unsigned rs = atomicAdd(&lcS[bs], 1u);
    ebuf2[lbS[bs] + (int)rs] = (unsigned char)(s & 127);
  }
}

// Fused per-bucket pass: (A) src-degree -> oi (kept in LDS for coi);
// (B) dst counts -> row_ptr/ii/coi (parallel 128-scan); (C) clustered csr_src fill.
__global__ __launch_bounds__(256) void k_buckets(const int* __restrict__ ebuf,
                                                 const unsigned char* __restrict__ ebuf2,
                                                 const int* __restrict__ bbase,
                                                 const int* __restrict__ sbase,
                                                 float* __restrict__ oi,
                                                 int* __restrict__ row_ptr,
                                                 int* __restrict__ csr_src,
                                                 float* __restrict__ ii,
                                                 float* __restrict__ coi) {
  __shared__ unsigned cntS[128];
  __shared__ unsigned cntD[128];
  __shared__ unsigned sc2[128];
  const int b = blockIdx.x, t = threadIdx.x;
  const int node0 = b << BSHIFT;
  if (t < 128) { cntS[t] = 0u; cntD[t] = 0u; }
  __syncthreads();
  const int sbeg = sbase[b], send = sbase[b + 1];
  for (int j = sbeg + t; j < send; j += 256)
    atomicAdd(&cntS[ebuf2[j]], 1u);
  const int base = bbase[b], end = bbase[b + 1];
  for (int j = base + t; j < end; j += 256)
    atomicAdd(&cntD[(unsigned)ebuf[j] >> 17], 1u);
  __syncthreads();
  unsigned cD = (t < 128) ? cntD[t] : 0u;
  if (t < 128) sc2[t] = cD;
  __syncthreads();
  for (int d = 1; d < 128; d <<= 1) {
    unsigned a = (t < 128 && t >= d) ? sc2[t - d] : 0u;
    __syncthreads();
    if (t < 128) sc2[t] += a;
    __syncthreads();
  }
  if (t < 128) {
    unsigned ex = sc2[t] - cD;  // exclusive prefix
    unsigned cs = cntS[t]; if (cs < 1u) cs = 1u;
    float o = rsqrtf((float)cs);
    int n = node0 + t;
    if (n < N_NODES) {
      oi[n] = o;
      row_ptr[n] = base + (int)ex;
      unsigned c = cD; if (c < 1u) c = 1u;
      float iv = rsqrtf((float)c);
      ii[n] = iv;
      coi[n] = iv * o;  // relu(ii*agg)*oi == (ii*oi)*relu(agg)
    }
    cntD[t] = ex;  // reuse as cursors
  }
  __syncthreads();
  for (int j = base + t; j < end; j += 256) {
    int pk = ebuf[j];
    unsigned dn = (unsigned)pk >> 17;
    unsigned slot = atomicAdd(&cntD[dn], 1u);
    csr_src[base + (int)slot] = pk & 0x1FFFF;
  }
}

// ---------------- GEMM1 (MFMA bf16): h1b = bf16((x*oi) @ W1), 100k x 128 x 128 ----------------

#define LPAD 136

__global__ __launch_bounds__(256) void k_gemm1(const float* __restrict__ x,
                                               const float* __restrict__ oi,
                                               const unsigned short* __restrict__ Wt1,
                                               unsigned short* __restrict__ h1b) {
  __shared__ unsigned short Xs[64 * LPAD];
  __shared__ unsigned short Ws[128 * LPAD];
  const int t = threadIdx.x;
  const int row0 = blockIdx.x * 64;
#pragma unroll
  for (int j = 0; j < 8; ++j) {
    int q = t + 256 * j;
    int n = q >> 4, c = q & 15;
    *(uint4*)(Ws + n * LPAD + c * 8) = *(const uint4*)(Wt1 + n * 128 + c * 8);
  }
#pragma unroll
  for (int j = 0; j < 4; ++j) {
    int q = t + 256 * j;
    int r = q >> 4, c = q & 15;
    int gr = row0 + r; if (gr >= N_NODES) gr = N_NODES - 1;
    const float* xp = x + (size_t)gr * 128 + c * 8;
    float4 v0 = *(const float4*)(xp);
    float4 v1 = *(const float4*)(xp + 4);
    float s = oi[gr];
    uint4 pk;
    pk.x = pack_bf16x2(v0.x * s, v0.y * s);
    pk.y = pack_bf16x2(v0.z * s, v0.w * s);
    pk.z = pack_bf16x2(v1.x * s, v1.y * s);
    pk.w = pack_bf16x2(v1.z * s, v1.w * s);
    *(uint4*)(Xs + r * LPAD + c * 8) = pk;
  }
  __syncthreads();
  const int w = t >> 6, lane = t & 63;
  const int m = lane & 15;
  const int q8 = (lane >> 4) * 8;
  f32x4 acc[8];
#pragma unroll
  for (int i = 0; i < 8; ++i) acc[i] = (f32x4){0.f, 0.f, 0.f, 0.f};
  const unsigned short* xrow = Xs + (w * 16 + m) * LPAD;
#pragma unroll
  for (int ks = 0; ks < 4; ++ks) {
    bf16x8 a = *(const bf16x8*)(xrow + ks * 32 + q8);
#pragma unroll
    for (int ct = 0; ct < 8; ++ct) {
      bf16x8 b = *(const bf16x8*)(Ws + (ct * 16 + m) * LPAD + ks * 32 + q8);
      acc[ct] = __builtin_amdgcn_mfma_f32_16x16x32_bf16(a, b, acc[ct], 0, 0, 0);
    }
  }
  const int rbase = row0 + w * 16 + (lane >> 4) * 4;
#pragma unroll
  for (int ct = 0; ct < 8; ++ct) {
    int coln = ct * 16 + m;
#pragma unroll
    for (int r = 0; r < 4; ++r) {
      int grow = rbase + r;
      if (grow < N_NODES) h1b[(size_t)grow * 128 + coln] = bf16u(acc[ct][r]);
    }
  }
}

// ---------------- AGG1: g = bf16(coi * relu(sum h1[src]))  (16 lanes/node, uint4, MLP 8/4/1) ----

__global__ __launch_bounds__(256) void k_agg1(const unsigned short* __restrict__ h1b,
                                              const int* __restrict__ csr_src,
                                              const int* __restrict__ row_ptr,
                                              const float* __restrict__ coi,
                                              unsigned short* __restrict__ g) {
  const int t = threadIdx.x;
  const int node = blockIdx.x * 16 + (t >> 4);
  const int c = t & 15;
  const int beg = row_ptr[node];
  const int end = row_ptr[node + 1];
  float4 a0 = make_float4(0.f, 0.f, 0.f, 0.f);
  float4 a1 = make_float4(0.f, 0.f, 0.f, 0.f);
  int j = beg;
  for (; j + 8 <= end; j += 8) {
    uint4 v[8];
#pragma unroll
    for (int i = 0; i < 8; ++i) {
      int s = csr_src[j + i];
      v[i] = *(const uint4*)(h1b + (size_t)s * 128 + 8 * c);
    }
#pragma unroll
    for (int i = 0; i < 8; ++i) {
      a0.x += bf_lo(v[i].x); a0.y += bf_hi(v[i].x);
      a0.z += bf_lo(v[i].y); a0.w += bf_hi(v[i].y);
      a1.x += bf_lo(v[i].z); a1.y += bf_hi(v[i].z);
      a1.z += bf_lo(v[i].w); a1.w += bf_hi(v[i].w);
    }
  }
  if (j + 4 <= end) {
    uint4 v[4];
#pragma unroll
    for (int i = 0; i < 4; ++i) {
      int s = csr_src[j + i];
      v[i] = *(const uint4*)(h1b + (size_t)s * 128 + 8 * c);
    }
#pragma unroll
    for (int i = 0; i < 4; ++i) {
      a0.x += bf_lo(v[i].x); a0.y += bf_hi(v[i].x);
      a0.z += bf_lo(v[i].y); a0.w += bf_hi(v[i].y);
      a1.x += bf_lo(v[i].z); a1.y += bf_hi(v[i].z);
      a1.z += bf_lo(v[i].w); a1.w += bf_hi(v[i].w);
    }
    j += 4;
  }
  for (; j < end; ++j) {
    int s = csr_src[j];
    uint4 v = *(const uint4*)(h1b + (size_t)s * 128 + 8 * c);
    a0.x += bf_lo(v.x); a0.y += bf_hi(v.x); a0.z += bf_lo(v.y); a0.w += bf_hi(v.y);
    a1.x += bf_lo(v.z); a1.y += bf_hi(v.z); a1.z += bf_lo(v.w); a1.w += bf_hi(v.w);
  }
  float sc = coi[node];
  uint4 pk;
  pk.x = pack_bf16x2(fmaxf(a0.x, 0.f) * sc, fmaxf(a0.y, 0.f) * sc);
  pk.y = pack_bf16x2(fmaxf(a0.z, 0.f) * sc, fmaxf(a0.w, 0.f) * sc);
  pk.z = pack_bf16x2(fmaxf(a1.x, 0.f) * sc, fmaxf(a1.y, 0.f) * sc);
  pk.w = pack_bf16x2(fmaxf(a1.z, 0.f) * sc, fmaxf(a1.w, 0.f) * sc);
  *(uint4*)(g + (size_t)node * 128 + 8 * c) = pk;
}

// ---------------- GEMM2 (MFMA bf16): h2b = bf16(g @ W2), 100k x 128 x 40 (N pad 48) ----------------

__global__ __launch_bounds__(256) void k_gemm2(const unsigned short* __restrict__ gb,
                                               const unsigned short* __restrict__ Wt2,
                                               unsigned short* __restrict__ h2b) {
  __shared__ unsigned short Gs[64 * LPAD];
  __shared__ unsigned short Ws[48 * LPAD];
  const int t = threadIdx.x;
  const int row0 = blockIdx.x * 64;
#pragma unroll
  for (int j = 0; j < 3; ++j) {
    int q = t + 256 * j;
    int n = q >> 4, c = q & 15;
    *(uint4*)(Ws + n * LPAD + c * 8) = *(const uint4*)(Wt2 + n * 128 + c * 8);
  }
#pragma unroll
  for (int j = 0; j < 4; ++j) {
    int q = t + 256 * j;
    int r = q >> 4, c = q & 15;
    int gr = row0 + r; if (gr >= N_NODES) gr = N_NODES - 1;
    *(uint4*)(Gs + r * LPAD + c * 8) = *(const uint4*)(gb + (size_t)gr * 128 + c * 8);
  }
  __syncthreads();
  const int w = t >> 6, lane = t & 63;
  const int m = lane & 15;
  const int q8 = (lane >> 4) * 8;
  f32x4 acc[3];
#pragma unroll
  for (int i = 0; i < 3; ++i) acc[i] = (f32x4){0.f, 0.f, 0.f, 0.f};
  const unsigned short* grow_p = Gs + (w * 16 + m) * LPAD;
#pragma unroll
  for (int ks = 0; ks < 4; ++ks) {
    bf16x8 a = *(const bf16x8*)(grow_p + ks * 32 + q8);
#pragma unroll
    for (int ct = 0; ct < 3; ++ct) {
      bf16x8 b = *(const bf16x8*)(Ws + (ct * 16 + m) * LPAD + ks * 32 + q8);
      acc[ct] = __builtin_amdgcn_mfma_f32_16x16x32_bf16(a, b, acc[ct], 0, 0, 0);
    }
  }
  const int rbase = row0 + w * 16 + (lane >> 4) * 4;
#pragma unroll
  for (int ct = 0; ct < 3; ++ct) {
    int coln = ct * 16 + m;
    if (coln < 40) {
#pragma unroll
      for (int r = 0; r < 4; ++r) {
        int grow = rbase + r;
        if (grow < N_NODES) h2b[(size_t)grow * 40 + coln] = bf16u(acc[ct][r]);
      }
    }
  }
}

// ---------------- AGG2: out = ii * sum h2[src]  (16-lane groups, uint2, MLP 16/8/4/1) ----------------

__global__ __launch_bounds__(256) void k_agg2(const unsigned short* __restrict__ h2b,
                                              const int* __restrict__ csr_src,
                                              const int* __restrict__ row_ptr,
                                              const float* __restrict__ ii,
                                              float* __restrict__ out) {
  const int t = threadIdx.x;
  const int node = blockIdx.x * 16 + (t >> 4);
  const int c = t & 15;
  if (c >= 10) return;
  const int beg = row_ptr[node];
  const int end = row_ptr[node + 1];
  float4 acc = make_float4(0.f, 0.f, 0.f, 0.f);
  int j = beg;
  for (; j + 16 <= end; j += 16) {
    uint2 v[16];
#pragma unroll
    for (int i = 0; i < 16; ++i) {
      int s = csr_src[j + i];
      v[i] = *(const uint2*)(h2b + (size_t)s * 40 + 4 * c);
    }
#pragma unroll
    for (int i = 0; i < 16; ++i) {
      acc.x += bf_lo(v[i].x); acc.y += bf_hi(v[i].x);
      acc.z += bf_lo(v[i].y); acc.w += bf_hi(v[i].y);
    }
  }
  if (j + 8 <= end) {
    uint2 v[8];
#pragma unroll
    for (int i = 0; i < 8; ++i) {
      int s = csr_src[j + i];
      v[i] = *(const uint2*)(h2b + (size_t)s * 40 + 4 * c);
    }
#pragma unroll
    for (int i = 0; i < 8; ++i) {
      acc.x += bf_lo(v[i].x); acc.y += bf_hi(v[i].x);
      acc.z += bf_lo(v[i].y); acc.w += bf_hi(v[i].y);
    }
    j += 8;
  }
  if (j + 4 <= end) {
    uint2 v[4];
#pragma unroll
    for (int i = 0; i < 4; ++i) {
      int s = csr_src[j + i];
      v[i] = *(const uint2*)(h2b + (size_t)s * 40 + 4 * c);
    }
#pragma unroll
    for (int i = 0; i < 4; ++i) {
      acc.x += bf_lo(v[i].x); acc.y += bf_hi(v[i].x);
      acc.z += bf_lo(v[i].y); acc.w += bf_hi(v[i].y);
    }
    j += 4;
  }
  for (; j < end; ++j) {
    int s = csr_src[j];
    uint2 v = *(const uint2*)(h2b + (size_t)s * 40 + 4 * c);
    acc.x += bf_lo(v.x); acc.y += bf_hi(v.x); acc.z += bf_lo(v.y); acc.w += bf_hi(v.y);
  }
  float sc = ii[node];
  acc.x *= sc; acc.y *= sc; acc.z *= sc; acc.w *= sc;
  *(float4*)(out + (size_t)node * 40 + 4 * c) = acc;
}

// ---------------- launch ----------------

extern "C" void kernel_launch(void* const* d_in, const int* in_sizes, int n_in,
                              void* d_out, int out_size, void* d_ws, size_t ws_size,
                              hipStream_t stream) {
  const float* x  = (const float*)d_in[0];
  const int* ei   = (const int*)d_in[1];
  const float* W1 = (const float*)d_in[2];
  const float* W2 = (const float*)d_in[3];
  const int* src = ei;
  const int* dst = ei + N_EDGES;
  float* out = (float*)d_out;

  char* p = (char*)d_ws;
  auto alloc = [&](size_t b) -> void* {
    char* r = p;
    p += (b + 255) & ~(size_t)255;
    return (void*)r;
  };
  float* oi             = (float*)alloc((size_t)N_NODES * 4);
  float* ii             = (float*)alloc((size_t)N_NODES * 4);
  float* coi            = (float*)alloc((size_t)N_NODES * 4);
  int* row_ptr          = (int*)alloc((size_t)(N_NODES + 1) * 4);
  unsigned* histGd      = (unsigned*)alloc((size_t)NBUCK * NCHUNK * 4);
  unsigned* histGs      = (unsigned*)alloc((size_t)NBUCK * NCHUNK * 4);
  unsigned* btot        = (unsigned*)alloc((size_t)2 * NBUCK * 4);
  int* bbase            = (int*)alloc((size_t)(NBUCK + 1) * 4);
  int* sbase            = (int*)alloc((size_t)(NBUCK + 1) * 4);
  int* ebuf             = (int*)alloc((size_t)N_EDGES * 4);
  unsigned char* ebuf2  = (unsigned char*)alloc((size_t)N_EDGES);
  int* csr_src          = (int*)alloc((size_t)N_EDGES * 4);
  unsigned short* Wt1   = (unsigned short*)alloc((size_t)128 * 128 * 2);
  unsigned short* Wt2   = (unsigned short*)alloc((size_t)48 * 128 * 2);
  unsigned short* h1b   = (unsigned short*)alloc((size_t)N_NODES * 128 * 2);
  unsigned short* g     = (unsigned short*)alloc((size_t)N_NODES * 128 * 2);
  unsigned short* h2b   = (unsigned short*)alloc((size_t)N_NODES * 40 * 2);

  k_hist<<<NCHUNK, 256, 0, stream>>>(src, dst, histGd, histGs, W1, W2, Wt1, Wt2);
  k_offs<<<2 * NBUCK, 256, 0, stream>>>(histGd, histGs, btot);
  k_bscan2<<<2, 1024, 0, stream>>>(btot, bbase, sbase, row_ptr);
  k_part<<<NCHUNK, 256, 0, stream>>>(src, dst, histGd, histGs, bbase, sbase, ebuf, ebuf2);
  k_buckets<<<NBUCK, 256, 0, stream>>>(ebuf, ebuf2, bbase, sbase, oi, row_ptr, csr_src,
                                       ii, coi);
  k_gemm1<<<(N_NODES + 63) / 64, 256, 0, stream>>>(x, oi, Wt1, h1b);
  k_agg1<<<N_NODES / 16, 256, 0, stream>>>(h1b, csr_src, row_ptr, coi, g);
  k_gemm2<<<(N_NODES + 63) / 64, 256, 0, stream>>>(g, Wt2, h2b);
  k_agg2<<<N_NODES / 16, 256, 0, stream>>>(h2b, csr_src, row_ptr, ii, out);
}